// Round 4
// baseline (561.778 us; speedup 1.0000x reference)
//
#include <hip/hip_runtime.h>

// GroupGSDConv round 8: dilation-pure compressed items.
// Channels sorted by dilation => each dilation = contiguous run in perm.
// Items = one per distinct dilation (run split at 32 if needed, <=7 total);
// A-rows = run compressed to rows 0..g-1, zero-padded to 32. No more
// zero-masked cross-dilation waste (was 3.5x) and no octile imbalance
// (was cnt=3 vs 4 -> 25% idle at barriers). Waves = 8 y-pairs (rt=2),
// each wave runs the identical item list over all 64 oc.
// acc[7][2] floatx16 lives across the ks loop (static indices only).
// Staging (ks-plane xb16 + global_load_lds + 2-phase dbuf + XCD swizzle)
// unchanged from round 7. Stores masked by row<g, oc = perm[start+row].

#define HW_ 128
#define C_ 64
#define B_ 16
#define EX 44
#define EY 28
#define NPIX (EY * EX)              // 1232 staged pixels
#define NSETS 39                    // ceil(2464/64) wave-chunk sets
#define BUFDW (NSETS * 64 * 4)      // 9984 dwords = 39936 B per buffer
#define PADW 140
#define PLANE_STRIDE (PADW * PADW * 16)  // shorts per ks-plane (313600)
#define MAX_ITEMS 12
#define ITEMS_MAX 7                 // >=1 split only possible if one g>32
#define WS_WPACK_OFF 1024
#define WS_XB16_OFF (1 << 20)
#define XB16_BYTES ((size_t)B_ * 4 * PLANE_STRIDE * 2)  // 40,140,800

// desc layout (ints):
//  [0..63]   perm (sorted-by-dilation channel ids)
//  [64]      cnt (number of items)
//  [66+i]    dilation of item i      (i < 12)
//  [78+i]    start of item i in perm
//  [90+i]    g (row count) of item i

typedef __attribute__((ext_vector_type(8))) short short8;
typedef __attribute__((ext_vector_type(16))) float floatx16;

__device__ __forceinline__ unsigned bf16rne(float f) {
  unsigned u = __float_as_uint(f);
  return (u + 0x7FFFu + ((u >> 16) & 1u)) >> 16;  // round-nearest-even
}

#define GLOAD_LDS16(g, l)                                   \
  __builtin_amdgcn_global_load_lds(                         \
      (const __attribute__((address_space(1))) void*)(g),   \
      (__attribute__((address_space(3))) void*)(l), 16, 0, 0)

__global__ __launch_bounds__(256) void gsd_prep(
    const float* __restrict__ x, const int* __restrict__ offsets,
    const float* __restrict__ w, int* __restrict__ desc,
    uint4* __restrict__ wpack, unsigned short* __restrict__ xb16,
    const int nrow) {
  const int bid = blockIdx.x;
  const int tid = threadIdx.x;

  if (bid < nrow) {
    // ---- transpose+convert one padded row into 4 ks-planes ----
    // per plane-row: 140 px * 16 ch * 2B = 4480 B = 280 uint4 (2/px)
    const int b = bid / PADW, py = bid - b * PADW;
    uint4* o4 = (uint4*)xb16;
    const size_t pb0 = ((size_t)b * 4) * 39200 + (size_t)py * 280;
    const uint4 z = make_uint4(0, 0, 0, 0);
    if (py < 6 || py >= PADW - 6) {
      for (int i = tid; i < 1120; i += 256) {
        const int ks = i / 280, r = i - ks * 280;
        o4[pb0 + (size_t)ks * 39200 + r] = z;
      }
      return;
    }
    // x-pads: per plane-row, uint4 0..11 and 268..279
    if (tid < 96) {
      const int ks = tid / 24, rr = tid - ks * 24;
      const int idx = rr < 12 ? rr : 256 + rr;
      o4[pb0 + (size_t)ks * 39200 + idx] = z;
    }
    const int y = py - 6;
    __shared__ unsigned l32[128 * 33];  // [x][c-pair], +1 pad
    const int xx = tid & 127, ph = tid >> 7;
    const float* xp = x + (size_t)b * (C_ * HW_ * HW_) + y * HW_ + xx;
#pragma unroll 4
    for (int p = ph; p < 32; p += 2) {
      const float v0 = xp[(2 * p) * (HW_ * HW_)];
      const float v1 = xp[(2 * p + 1) * (HW_ * HW_)];
      l32[xx * 33 + p] = bf16rne(v0) | (bf16rne(v1) << 16);
    }
    __syncthreads();
#pragma unroll 4
    for (int ch = tid; ch < 1024; ch += 256) {  // 4 planes * 128 px * 2
      const int ks = ch >> 8, r = ch & 255;
      const unsigned* s = &l32[(r >> 1) * 33 + ks * 8 + (r & 1) * 4];
      o4[pb0 + (size_t)ks * 39200 + 12 + r] = make_uint4(s[0], s[1], s[2], s[3]);
    }
    return;
  }

  // ---- setup role (tail blocks; every block recomputes sd) ----
  __shared__ int sd[128];
  __shared__ int soffs[C_];
  if (tid < C_) soffs[tid] = offsets[tid];
  __syncthreads();
  if (tid < C_) {  // parallel stable rank sort by (dilation, channel)
    const int key = soffs[tid];
    int rank = 0;
    for (int c = 0; c < C_; ++c) {
      const int kc = soffs[c];
      rank += (int)((kc < key) | ((kc == key) & (c < tid)));
    }
    sd[rank] = tid;
  }
  __syncthreads();
  if (tid == 0) {
    // dilation-pure items: one per contiguous run (split at 32 rows)
    int ni = 0, c = 0;
    while (c < C_ && ni < MAX_ITEMS) {
      const int d = soffs[sd[c]];
      int e = c;
      while (e < C_ && soffs[sd[e]] == d) ++e;  // run [c, e)
      for (int st = c; st < e && ni < MAX_ITEMS; st += 32) {
        sd[66 + ni] = d;
        sd[78 + ni] = st;
        sd[90 + ni] = (e - st) < 32 ? (e - st) : 32;
        ++ni;
      }
      c = e;
    }
    sd[64] = ni;
  }
  __syncthreads();

  const int sbid = bid - nrow;
  if (sbid == 0) {
    if (tid < 102) desc[tid] = sd[tid];
    return;
  }
  const int wix = sbid - 1;
  if (wix >= sd[64]) return;
  const int start = sd[78 + wix];
  const int g = sd[90 + wix];

  // Pack A-frags: wpack[wix*2304 + ((ks*9+tap)*64+lane)], element layout
  // m = lane&31 (compressed row), k = (lane>>5)*8 + j, ic = ks*16 + k.
  for (int i = tid; i < 4 * 9 * 64; i += 256) {
    const int ks = i / 576;
    const int r = i % 576;
    const int tap = r >> 6;
    const int lane = r & 63;
    const int m = lane & 31, hh = lane >> 5;
    const bool act = m < g;
    const int oc = act ? sd[start + m] : 0;
    unsigned ww[4];
    for (int jj = 0; jj < 4; ++jj) {
      float v0 = 0.f, v1 = 0.f;
      if (act) {
        const int ic0 = ks * 16 + hh * 8 + jj * 2;
        v0 = w[(oc * C_ + ic0) * 9 + tap];
        v1 = w[(oc * C_ + ic0 + 1) * 9 + tap];
      }
      ww[jj] = bf16rne(v0) | (bf16rne(v1) << 16);
    }
    wpack[(size_t)wix * 2304 + i] = make_uint4(ww[0], ww[1], ww[2], ww[3]);
  }
}

template <bool PRE>
__global__ __launch_bounds__(512, 4) void gsd_conv(
    const float* __restrict__ x, const unsigned short* __restrict__ xb16,
    const int* __restrict__ desc, const uint4* __restrict__ wpack,
    float* __restrict__ out) {
  const int tid = threadIdx.x;
  const int bid0 = blockIdx.x;
  const int gxid = (bid0 & 7) * 64 + (bid0 >> 3);  // XCD swizzle (512%8==0)
  const int b = gxid >> 5;
  const int yt = (gxid >> 2) & 7;
  const int xt = gxid & 3;
  const int y0 = yt * 16, x0 = xt * 32;

  const int lane = tid & 63;
  const int n = lane & 31;   // MFMA B col -> output x
  const int h = lane >> 5;   // k-half
  const int wv = tid >> 6;   // 8 waves = 8 y-pairs
  const int yb = wv * 2;     // this wave's rows: yb, yb+1

  __shared__ __align__(16) unsigned ldsbuf[2][BUFDW];  // 79872 B, 2 blk/CU

  floatx16 acc[ITEMS_MAX][2];
#pragma unroll
  for (int s = 0; s < ITEMS_MAX; ++s)
#pragma unroll
    for (int rt = 0; rt < 2; ++rt)
#pragma unroll
      for (int e = 0; e < 16; ++e) acc[s][rt][e] = 0.f;

  // ---- per-path staging precompute ----
  const unsigned short* xbase;
  int srcoff[5];
  if constexpr (PRE) {
    // Chunk q = (wv + j*8)*64 + lane; LDS dst byte = q*16 (linear).
    // Slot (pix, p) holds logical ic-half p ^ f(pix), f(pix)=(pix>>2)&1
    // (bank swizzle realized via the per-lane global source address).
    xbase = xb16 + (size_t)b * 4 * PLANE_STRIDE;
#pragma unroll
    for (int j = 0; j < 5; ++j) {
      const int q = (wv + j * 8) * 64 + lane;
      int pix = q >> 1;
      if (pix > NPIX - 1) pix = NPIX - 1;  // set-38 tail -> pad, src clamped
      const int p = q & 1;
      const int yy = pix / EX, xx = pix - yy * EX;
      const int half = p ^ ((pix >> 2) & 1);
      srcoff[j] = ((y0 + yy) * PADW + (x0 + xx)) * 16 + half * 8;
    }
  }
  int slx, sq, sy2, gxc;
  bool xin;
  const float* xb;
  if constexpr (!PRE) {
    slx = tid & 63;
    sq = (tid >> 6) & 3;
    sy2 = tid >> 8;
    xb = x + (size_t)b * (C_ * HW_ * HW_);
    const int gx = x0 - 6 + slx;
    gxc = gx < 0 ? 0 : (gx > 127 ? 127 : gx);
    xin = ((unsigned)gx < 128u) & (slx < EX);
  }

  const int cnt = __builtin_amdgcn_readfirstlane(desc[64]);

  // ---- staging: 5 async 16B chunks/wave (wave 7: 4), zero VALU ----
  auto STAGE = [&](int buf, int ks) {
    if constexpr (PRE) {
      const unsigned short* xp = xbase + (size_t)ks * PLANE_STRIDE;
#pragma unroll
      for (int j = 0; j < 5; ++j) {
        if (j < 4) {
          GLOAD_LDS16(xp + srcoff[j], &ldsbuf[buf][(wv + j * 8) * 256]);
        } else if (wv < 7) {  // sets 32..38 only
          GLOAD_LDS16(xp + srcoff[4], &ldsbuf[buf][(wv + 32) * 256]);
        }
      }
    }
  };

  // ---- compute: all items (dilation-pure rows), 9 taps x 2 y-rows ----
  auto COMPUTE = [&](const unsigned* cbuf, int ks) {
#pragma unroll
    for (int s = 0; s < ITEMS_MAX; ++s) {
      if (s < cnt) {
        const int d = __builtin_amdgcn_readfirstlane(desc[66 + s]);
        const uint4* wp = wpack + ((size_t)s * 4 + ks) * 576 + lane;
#pragma unroll
        for (int tap = 0; tap < 9; ++tap) {
          const int ky = tap / 3 - 1, kx = tap % 3 - 1;
          const short8 af = __builtin_bit_cast(short8, wp[tap * 64]);
          const int prow = yb + ky * d + 6;
          const int pxb = n + kx * d + 6;
#pragma unroll
          for (int rt = 0; rt < 2; ++rt) {
            const int pix = (prow + rt) * EX + pxb;
            const int dws = (pix << 3) + ((h ^ ((pix >> 2) & 1)) << 2);
            const short8 bf = *reinterpret_cast<const short8*>(&cbuf[dws]);
            acc[s][rt] = __builtin_amdgcn_mfma_f32_32x32x16_bf16(
                af, bf, acc[s][rt], 0, 0, 0);
          }
        }
      }
    }
  };

  if constexpr (PRE) {
    // 2-phase pipeline: stage(ks+1) issued before compute(ks); one
    // barrier per ks (drains vmcnt -> staged buffer valid next iter).
    STAGE(0, 0);
    __syncthreads();
#pragma unroll
    for (int ks = 0; ks < 3; ++ks) {
      STAGE((ks + 1) & 1, ks + 1);
      COMPUTE(ldsbuf[ks & 1], ks);
      __syncthreads();
    }
    COMPUTE(ldsbuf[1], 3);
  } else {
    for (int ks = 0; ks < 4; ++ks) {
      if (ks) __syncthreads();
      // fallback: fp32->bf16 in-kernel staging, single buffer
      const float* xp = xb + (size_t)(ks * 16 + sq * 4) * (HW_ * HW_);
#pragma unroll 2
      for (int yy = sy2; yy < EY; yy += 2) {
        const int gy = y0 - 6 + yy;
        const int gyc = gy < 0 ? 0 : (gy > 127 ? 127 : gy);
        const bool ok = xin & ((unsigned)gy < 128u);
        const float* p = xp + gyc * HW_ + gxc;
        float v0 = p[0];
        float v1 = p[HW_ * HW_];
        float v2 = p[2 * HW_ * HW_];
        float v3 = p[3 * HW_ * HW_];
        if (!ok) { v0 = v1 = v2 = v3 = 0.f; }
        const unsigned lo = bf16rne(v0) | (bf16rne(v1) << 16);
        const unsigned hi = bf16rne(v2) | (bf16rne(v3) << 16);
        if (slx < EX) {
          const int pix = yy * EX + slx;
          const int dws =
              pix * 8 + (((sq >> 1) ^ ((pix >> 2) & 1)) << 2) + ((sq & 1) << 1);
          *reinterpret_cast<uint2*>(&ldsbuf[0][dws]) = make_uint2(lo, hi);
        }
      }
      __syncthreads();
      COMPUTE(ldsbuf[0], ks);
    }
  }

  // ---- store: D col=lane&31 -> x, row=(reg&3)+8*(reg>>2)+4*h ----
  // row is the compressed item row; mask row<g, oc = perm[start+row].
#pragma unroll
  for (int s = 0; s < ITEMS_MAX; ++s) {
    if (s < cnt) {
      const int start = __builtin_amdgcn_readfirstlane(desc[78 + s]);
      const int g = __builtin_amdgcn_readfirstlane(desc[90 + s]);
#pragma unroll
      for (int reg = 0; reg < 16; ++reg) {
        const int row = (reg & 3) + 8 * (reg >> 2) + 4 * h;
        if (row < g) {
          const int oc = desc[start + row];
#pragma unroll
          for (int rt = 0; rt < 2; ++rt) {
            out[((size_t)(b * C_ + oc) * HW_ + (y0 + yb + rt)) * HW_ + x0 + n] =
                acc[s][rt][reg];
          }
        }
      }
    }
  }
}

extern "C" void kernel_launch(void* const* d_in, const int* in_sizes, int n_in,
                              void* d_out, int out_size, void* d_ws,
                              size_t ws_size, hipStream_t stream) {
  const float* x = (const float*)d_in[0];    // [16,64,128,128] fp32
  const float* w = (const float*)d_in[1];    // [64,64,3,3] fp32
  const int* offsets = (const int*)d_in[2];  // [64] int32 in [1,6]
  float* out = (float*)d_out;                // [16,64,128,128] fp32

  int* desc = (int*)d_ws;
  uint4* wpack = (uint4*)((char*)d_ws + WS_WPACK_OFF);  // 442368 B
  unsigned short* xb16 = (unsigned short*)((char*)d_ws + WS_XB16_OFF);

  // Fast path needs 1 MB (desc+wpack) + 40.1 MB (xb16) of workspace.
  const bool pre = ws_size >= (size_t)WS_XB16_OFF + XB16_BYTES;
  const int nrow = pre ? B_ * PADW : 0;

  gsd_prep<<<dim3(nrow + 1 + MAX_ITEMS), 256, 0, stream>>>(
      x, offsets, w, desc, wpack, xb16, nrow);
  if (pre) {
    gsd_conv<true><<<dim3(B_ * 8 * 4), 512, 0, stream>>>(
        x, xb16, desc, wpack, out);
  } else {
    gsd_conv<false><<<dim3(B_ * 8 * 4), 512, 0, stream>>>(
        x, xb16, desc, wpack, out);
  }
}

// Round 5
// 203.965 us; speedup vs baseline: 2.7543x; 2.7543x over previous
//
#include <hip/hip_runtime.h>

// GroupGSDConv round 9: dilation-pure items, ITEM-OUTER schedule.
// Round-8 post-mortem: acc[7][2] (224 VGPR) under launch_bounds(512,4)
// (128-VGPR cap) spilled to scratch -> 1.3GB HBM writes, 5x regression.
// Fix: stage ALL 4 ks-planes into LDS up front (4 x 39936B = 156KB ->
// 1 block/CU, 8 waves = 2/SIMD, 256-VGPR budget), ONE barrier, then
//   for item s: { acc0,acc1=0; for ks,tap: mfma; store s }
// Only one item's accumulator (32 VGPR) is ever live. Zero barriers in
// the compute phase; 432 MFMAs/wave straight-line (vs 576 in round 7,
// which also had cnt imbalance bubbles).
// Staging, ks-plane xb16 layout, source-baked bank swizzle f(pix)=
// (pix>>2)&1, XCD swizzle: unchanged from round 7 (verified 80us/21MB).
// Fallback (small ws): stages the same 4 planes via fp32 loads + VALU
// convert, then the identical item-outer compute (no spill either).

#define HW_ 128
#define C_ 64
#define B_ 16
#define EX 44
#define EY 28
#define NPIX (EY * EX)              // 1232 staged pixels
#define NSETS 39                    // ceil(2464/64) wave-chunk sets
#define BUFDW (NSETS * 64 * 4)      // 9984 dwords = 39936 B per plane
#define PADW 140
#define PLANE_STRIDE (PADW * PADW * 16)  // shorts per ks-plane (313600)
#define MAX_ITEMS 12
#define WS_WPACK_OFF 1024
#define WS_XB16_OFF (1 << 20)
#define XB16_BYTES ((size_t)B_ * 4 * PLANE_STRIDE * 2)  // 40,140,800

// desc layout (ints):
//  [0..63]   perm (sorted-by-dilation channel ids)
//  [64]      cnt (number of items)
//  [66+i]    dilation of item i      (i < 12)
//  [78+i]    start of item i in perm
//  [90+i]    g (row count) of item i

typedef __attribute__((ext_vector_type(8))) short short8;
typedef __attribute__((ext_vector_type(16))) float floatx16;

__device__ __forceinline__ unsigned bf16rne(float f) {
  unsigned u = __float_as_uint(f);
  return (u + 0x7FFFu + ((u >> 16) & 1u)) >> 16;  // round-nearest-even
}

#define GLOAD_LDS16(g, l)                                   \
  __builtin_amdgcn_global_load_lds(                         \
      (const __attribute__((address_space(1))) void*)(g),   \
      (__attribute__((address_space(3))) void*)(l), 16, 0, 0)

__global__ __launch_bounds__(256) void gsd_prep(
    const float* __restrict__ x, const int* __restrict__ offsets,
    const float* __restrict__ w, int* __restrict__ desc,
    uint4* __restrict__ wpack, unsigned short* __restrict__ xb16,
    const int nrow) {
  const int bid = blockIdx.x;
  const int tid = threadIdx.x;

  if (bid < nrow) {
    // ---- transpose+convert one padded row into 4 ks-planes ----
    // per plane-row: 140 px * 16 ch * 2B = 4480 B = 280 uint4 (2/px)
    const int b = bid / PADW, py = bid - b * PADW;
    uint4* o4 = (uint4*)xb16;
    const size_t pb0 = ((size_t)b * 4) * 39200 + (size_t)py * 280;
    const uint4 z = make_uint4(0, 0, 0, 0);
    if (py < 6 || py >= PADW - 6) {
      for (int i = tid; i < 1120; i += 256) {
        const int ks = i / 280, r = i - ks * 280;
        o4[pb0 + (size_t)ks * 39200 + r] = z;
      }
      return;
    }
    // x-pads: per plane-row, uint4 0..11 and 268..279
    if (tid < 96) {
      const int ks = tid / 24, rr = tid - ks * 24;
      const int idx = rr < 12 ? rr : 256 + rr;
      o4[pb0 + (size_t)ks * 39200 + idx] = z;
    }
    const int y = py - 6;
    __shared__ unsigned l32[128 * 33];  // [x][c-pair], +1 pad
    const int xx = tid & 127, ph = tid >> 7;
    const float* xp = x + (size_t)b * (C_ * HW_ * HW_) + y * HW_ + xx;
#pragma unroll 4
    for (int p = ph; p < 32; p += 2) {
      const float v0 = xp[(2 * p) * (HW_ * HW_)];
      const float v1 = xp[(2 * p + 1) * (HW_ * HW_)];
      l32[xx * 33 + p] = bf16rne(v0) | (bf16rne(v1) << 16);
    }
    __syncthreads();
#pragma unroll 4
    for (int ch = tid; ch < 1024; ch += 256) {  // 4 planes * 128 px * 2
      const int ks = ch >> 8, r = ch & 255;
      const unsigned* s = &l32[(r >> 1) * 33 + ks * 8 + (r & 1) * 4];
      o4[pb0 + (size_t)ks * 39200 + 12 + r] = make_uint4(s[0], s[1], s[2], s[3]);
    }
    return;
  }

  // ---- setup role (tail blocks; every block recomputes sd) ----
  __shared__ int sd[128];
  __shared__ int soffs[C_];
  if (tid < C_) soffs[tid] = offsets[tid];
  __syncthreads();
  if (tid < C_) {  // parallel stable rank sort by (dilation, channel)
    const int key = soffs[tid];
    int rank = 0;
    for (int c = 0; c < C_; ++c) {
      const int kc = soffs[c];
      rank += (int)((kc < key) | ((kc == key) & (c < tid)));
    }
    sd[rank] = tid;
  }
  __syncthreads();
  if (tid == 0) {
    // dilation-pure items: one per contiguous run (split at 32 rows)
    int ni = 0, c = 0;
    while (c < C_ && ni < MAX_ITEMS) {
      const int d = soffs[sd[c]];
      int e = c;
      while (e < C_ && soffs[sd[e]] == d) ++e;  // run [c, e)
      for (int st = c; st < e && ni < MAX_ITEMS; st += 32) {
        sd[66 + ni] = d;
        sd[78 + ni] = st;
        sd[90 + ni] = (e - st) < 32 ? (e - st) : 32;
        ++ni;
      }
      c = e;
    }
    sd[64] = ni;
  }
  __syncthreads();

  const int sbid = bid - nrow;
  if (sbid == 0) {
    if (tid < 102) desc[tid] = sd[tid];
    return;
  }
  const int wix = sbid - 1;
  if (wix >= sd[64]) return;
  const int start = sd[78 + wix];
  const int g = sd[90 + wix];

  // Pack A-frags: wpack[wix*2304 + ((ks*9+tap)*64+lane)], element layout
  // m = lane&31 (compressed row), k = (lane>>5)*8 + j, ic = ks*16 + k.
  for (int i = tid; i < 4 * 9 * 64; i += 256) {
    const int ks = i / 576;
    const int r = i % 576;
    const int tap = r >> 6;
    const int lane = r & 63;
    const int m = lane & 31, hh = lane >> 5;
    const bool act = m < g;
    const int oc = act ? sd[start + m] : 0;
    unsigned ww[4];
    for (int jj = 0; jj < 4; ++jj) {
      float v0 = 0.f, v1 = 0.f;
      if (act) {
        const int ic0 = ks * 16 + hh * 8 + jj * 2;
        v0 = w[(oc * C_ + ic0) * 9 + tap];
        v1 = w[(oc * C_ + ic0 + 1) * 9 + tap];
      }
      ww[jj] = bf16rne(v0) | (bf16rne(v1) << 16);
    }
    wpack[(size_t)wix * 2304 + i] = make_uint4(ww[0], ww[1], ww[2], ww[3]);
  }
}

template <bool PRE>
__global__ __launch_bounds__(512, 2) void gsd_conv(
    const float* __restrict__ x, const unsigned short* __restrict__ xb16,
    const int* __restrict__ desc, const uint4* __restrict__ wpack,
    float* __restrict__ out) {
  const int tid = threadIdx.x;
  const int bid0 = blockIdx.x;
  const int gxid = (bid0 & 7) * 64 + (bid0 >> 3);  // XCD swizzle (512%8==0)
  const int b = gxid >> 5;
  const int yt = (gxid >> 2) & 7;
  const int xt = gxid & 3;
  const int y0 = yt * 16, x0 = xt * 32;

  const int lane = tid & 63;
  const int n = lane & 31;   // MFMA B col -> output x
  const int h = lane >> 5;   // k-half
  const int wv = tid >> 6;   // 8 waves = 8 y-pairs
  const int yb = wv * 2;     // this wave's rows: yb, yb+1

  // all 4 ks-planes resident: 159744 B -> 1 block/CU, 8 waves (2/SIMD)
  __shared__ __align__(16) unsigned ldsbuf[4 * BUFDW];

  if constexpr (PRE) {
    // ---- stage all 4 planes: 20 async 16B chunks/wave, zero VALU ----
    // Chunk q = (wv + j*8)*64 + lane; LDS dst byte (in plane) = q*16.
    // Slot (pix, p) holds logical ic-half p ^ f(pix), f(pix)=(pix>>2)&1
    // (bank swizzle realized via the per-lane global source address).
    const unsigned short* xbase = xb16 + (size_t)b * 4 * PLANE_STRIDE;
    int srcoff[5];
#pragma unroll
    for (int j = 0; j < 5; ++j) {
      const int q = (wv + j * 8) * 64 + lane;
      int pix = q >> 1;
      if (pix > NPIX - 1) pix = NPIX - 1;  // set-38 tail -> pad, src clamped
      const int p = q & 1;
      const int yy = pix / EX, xx = pix - yy * EX;
      const int half = p ^ ((pix >> 2) & 1);
      srcoff[j] = ((y0 + yy) * PADW + (x0 + xx)) * 16 + half * 8;
    }
#pragma unroll
    for (int ks = 0; ks < 4; ++ks) {
      const unsigned short* xp = xbase + (size_t)ks * PLANE_STRIDE;
#pragma unroll
      for (int j = 0; j < 5; ++j) {
        if (j < 4) {
          GLOAD_LDS16(xp + srcoff[j],
                      &ldsbuf[ks * BUFDW + (wv + j * 8) * 256]);
        } else if (wv < 7) {  // sets 32..38 only
          GLOAD_LDS16(xp + srcoff[4], &ldsbuf[ks * BUFDW + (wv + 32) * 256]);
        }
      }
    }
  } else {
    // ---- fallback: stage 4 planes via fp32 loads + VALU convert ----
    const int slx = tid & 63;
    const int sq = (tid >> 6) & 3;
    const int sy2 = tid >> 8;
    const float* xb = x + (size_t)b * (C_ * HW_ * HW_);
    const int gx = x0 - 6 + slx;
    const int gxc = gx < 0 ? 0 : (gx > 127 ? 127 : gx);
    const bool xin = ((unsigned)gx < 128u) & (slx < EX);
    for (int ks = 0; ks < 4; ++ks) {
      const float* xp = xb + (size_t)(ks * 16 + sq * 4) * (HW_ * HW_);
#pragma unroll 2
      for (int yy = sy2; yy < EY; yy += 2) {
        const int gy = y0 - 6 + yy;
        const int gyc = gy < 0 ? 0 : (gy > 127 ? 127 : gy);
        const bool ok = xin & ((unsigned)gy < 128u);
        const float* p = xp + gyc * HW_ + gxc;
        float v0 = p[0];
        float v1 = p[HW_ * HW_];
        float v2 = p[2 * HW_ * HW_];
        float v3 = p[3 * HW_ * HW_];
        if (!ok) { v0 = v1 = v2 = v3 = 0.f; }
        const unsigned lo = bf16rne(v0) | (bf16rne(v1) << 16);
        const unsigned hi = bf16rne(v2) | (bf16rne(v3) << 16);
        if (slx < EX) {
          const int pix = yy * EX + slx;
          const int dws = ks * BUFDW + pix * 8 +
                          (((sq >> 1) ^ ((pix >> 2) & 1)) << 2) +
                          ((sq & 1) << 1);
          *reinterpret_cast<uint2*>(&ldsbuf[dws]) = make_uint2(lo, hi);
        }
      }
    }
  }
  __syncthreads();  // single barrier; compute is barrier-free

  const int cnt = __builtin_amdgcn_readfirstlane(desc[64]);

  // ---- item-outer compute: only one item's acc (32 VGPR) live ----
  for (int s = 0; s < cnt; ++s) {
    const int d = __builtin_amdgcn_readfirstlane(desc[66 + s]);
    const int start = __builtin_amdgcn_readfirstlane(desc[78 + s]);
    const int g = __builtin_amdgcn_readfirstlane(desc[90 + s]);

    floatx16 acc0, acc1;
#pragma unroll
    for (int e = 0; e < 16; ++e) { acc0[e] = 0.f; acc1[e] = 0.f; }

#pragma unroll
    for (int ks = 0; ks < 4; ++ks) {
      const uint4* wp = wpack + ((size_t)s * 4 + ks) * 576 + lane;
      const unsigned* cbuf = &ldsbuf[ks * BUFDW];
#pragma unroll
      for (int tap = 0; tap < 9; ++tap) {
        const int ky = tap / 3 - 1, kx = tap % 3 - 1;
        const short8 af = __builtin_bit_cast(short8, wp[tap * 64]);
        const int prow = yb + ky * d + 6;
        const int pxb = n + kx * d + 6;
        const int pix0 = prow * EX + pxb;
        const int pix1 = pix0 + EX;
        const int dws0 = (pix0 << 3) + ((h ^ ((pix0 >> 2) & 1)) << 2);
        const int dws1 = (pix1 << 3) + ((h ^ ((pix1 >> 2) & 1)) << 2);
        const short8 bf0 = *reinterpret_cast<const short8*>(&cbuf[dws0]);
        const short8 bf1 = *reinterpret_cast<const short8*>(&cbuf[dws1]);
        acc0 = __builtin_amdgcn_mfma_f32_32x32x16_bf16(af, bf0, acc0, 0, 0, 0);
        acc1 = __builtin_amdgcn_mfma_f32_32x32x16_bf16(af, bf1, acc1, 0, 0, 0);
      }
    }

    // ---- store item s: D col=lane&31 -> x, row=(reg&3)+8*(reg>>2)+4*h ----
    // row is the compressed item row; mask row<g, oc = perm[start+row].
#pragma unroll
    for (int reg = 0; reg < 16; ++reg) {
      const int row = (reg & 3) + 8 * (reg >> 2) + 4 * h;
      if (row < g) {
        const int oc = desc[start + row];
        float* op =
            &out[((size_t)(b * C_ + oc) * HW_ + (y0 + yb)) * HW_ + x0 + n];
        op[0] = acc0[reg];
        op[HW_] = acc1[reg];
      }
    }
  }
}

extern "C" void kernel_launch(void* const* d_in, const int* in_sizes, int n_in,
                              void* d_out, int out_size, void* d_ws,
                              size_t ws_size, hipStream_t stream) {
  const float* x = (const float*)d_in[0];    // [16,64,128,128] fp32
  const float* w = (const float*)d_in[1];    // [64,64,3,3] fp32
  const int* offsets = (const int*)d_in[2];  // [64] int32 in [1,6]
  float* out = (float*)d_out;                // [16,64,128,128] fp32

  int* desc = (int*)d_ws;
  uint4* wpack = (uint4*)((char*)d_ws + WS_WPACK_OFF);  // 442368 B
  unsigned short* xb16 = (unsigned short*)((char*)d_ws + WS_XB16_OFF);

  // Fast path needs 1 MB (desc+wpack) + 40.1 MB (xb16) of workspace.
  const bool pre = ws_size >= (size_t)WS_XB16_OFF + XB16_BYTES;
  const int nrow = pre ? B_ * PADW : 0;

  gsd_prep<<<dim3(nrow + 1 + MAX_ITEMS), 256, 0, stream>>>(
      x, offsets, w, desc, wpack, xb16, nrow);
  if (pre) {
    gsd_conv<true><<<dim3(B_ * 8 * 4), 512, 0, stream>>>(
        x, xb16, desc, wpack, out);
  } else {
    gsd_conv<false><<<dim3(B_ * 8 * 4), 512, 0, stream>>>(
        x, xb16, desc, wpack, out);
  }
}

// Round 6
// 198.988 us; speedup vs baseline: 2.8232x; 1.0250x over previous
//
#include <hip/hip_runtime.h>

// GroupGSDConv round 10: item-outer compute at 4 waves/SIMD.
// Round-9 post-mortem: all-4-planes LDS (156KB) -> 1 block/CU, but 512
// threads = 8 waves = only 2 waves/SIMD -> ds_read->MFMA latency exposed,
// 93us (worse than round-7's 80us at 4 waves/SIMD).
// Fix: SAME tile (16y x 32x), SAME 156KB 4-plane LDS, but 1024-thread
// blocks = 16 waves = 4 waves/SIMD. Waves = 8 y-pairs x 2 item-parities;
// wave (yp,par) computes items s==par (mod 2) for rows 2yp,2yp+1.
// Per wave: ~3 items x 72 = 216 MFMAs, acc0/acc1 dual-chain ILP, only
// 32 acc VGPRs live (item-outer). launch_bounds(1024,4) -> 128-VGPR cap
// (round 9 measured 96 -> fits). Single barrier; compute barrier-free.
// Staging: 39 chunk-sets/plane; wave w takes sets {w, w+16, w+32(w<7)}.
// ks-plane xb16 layout, source-baked bank swizzle f(pix)=(pix>>2)&1,
// XCD swizzle, prep kernel: unchanged from round 9.

#define HW_ 128
#define C_ 64
#define B_ 16
#define EX 44
#define EY 28
#define NPIX (EY * EX)              // 1232 staged pixels
#define NSETS 39                    // ceil(2464/64) wave-chunk sets
#define BUFDW (NSETS * 64 * 4)      // 9984 dwords = 39936 B per plane
#define PADW 140
#define PLANE_STRIDE (PADW * PADW * 16)  // shorts per ks-plane (313600)
#define MAX_ITEMS 12
#define WS_WPACK_OFF 1024
#define WS_XB16_OFF (1 << 20)
#define XB16_BYTES ((size_t)B_ * 4 * PLANE_STRIDE * 2)  // 40,140,800

// desc layout (ints):
//  [0..63]   perm (sorted-by-dilation channel ids)
//  [64]      cnt (number of items)
//  [66+i]    dilation of item i      (i < 12)
//  [78+i]    start of item i in perm
//  [90+i]    g (row count) of item i

typedef __attribute__((ext_vector_type(8))) short short8;
typedef __attribute__((ext_vector_type(16))) float floatx16;

__device__ __forceinline__ unsigned bf16rne(float f) {
  unsigned u = __float_as_uint(f);
  return (u + 0x7FFFu + ((u >> 16) & 1u)) >> 16;  // round-nearest-even
}

#define GLOAD_LDS16(g, l)                                   \
  __builtin_amdgcn_global_load_lds(                         \
      (const __attribute__((address_space(1))) void*)(g),   \
      (__attribute__((address_space(3))) void*)(l), 16, 0, 0)

__global__ __launch_bounds__(256) void gsd_prep(
    const float* __restrict__ x, const int* __restrict__ offsets,
    const float* __restrict__ w, int* __restrict__ desc,
    uint4* __restrict__ wpack, unsigned short* __restrict__ xb16,
    const int nrow) {
  const int bid = blockIdx.x;
  const int tid = threadIdx.x;

  if (bid < nrow) {
    // ---- transpose+convert one padded row into 4 ks-planes ----
    // per plane-row: 140 px * 16 ch * 2B = 4480 B = 280 uint4 (2/px)
    const int b = bid / PADW, py = bid - b * PADW;
    uint4* o4 = (uint4*)xb16;
    const size_t pb0 = ((size_t)b * 4) * 39200 + (size_t)py * 280;
    const uint4 z = make_uint4(0, 0, 0, 0);
    if (py < 6 || py >= PADW - 6) {
      for (int i = tid; i < 1120; i += 256) {
        const int ks = i / 280, r = i - ks * 280;
        o4[pb0 + (size_t)ks * 39200 + r] = z;
      }
      return;
    }
    // x-pads: per plane-row, uint4 0..11 and 268..279
    if (tid < 96) {
      const int ks = tid / 24, rr = tid - ks * 24;
      const int idx = rr < 12 ? rr : 256 + rr;
      o4[pb0 + (size_t)ks * 39200 + idx] = z;
    }
    const int y = py - 6;
    __shared__ unsigned l32[128 * 33];  // [x][c-pair], +1 pad
    const int xx = tid & 127, ph = tid >> 7;
    const float* xp = x + (size_t)b * (C_ * HW_ * HW_) + y * HW_ + xx;
#pragma unroll 4
    for (int p = ph; p < 32; p += 2) {
      const float v0 = xp[(2 * p) * (HW_ * HW_)];
      const float v1 = xp[(2 * p + 1) * (HW_ * HW_)];
      l32[xx * 33 + p] = bf16rne(v0) | (bf16rne(v1) << 16);
    }
    __syncthreads();
#pragma unroll 4
    for (int ch = tid; ch < 1024; ch += 256) {  // 4 planes * 128 px * 2
      const int ks = ch >> 8, r = ch & 255;
      const unsigned* s = &l32[(r >> 1) * 33 + ks * 8 + (r & 1) * 4];
      o4[pb0 + (size_t)ks * 39200 + 12 + r] = make_uint4(s[0], s[1], s[2], s[3]);
    }
    return;
  }

  // ---- setup role (tail blocks; every block recomputes sd) ----
  __shared__ int sd[128];
  __shared__ int soffs[C_];
  if (tid < C_) soffs[tid] = offsets[tid];
  __syncthreads();
  if (tid < C_) {  // parallel stable rank sort by (dilation, channel)
    const int key = soffs[tid];
    int rank = 0;
    for (int c = 0; c < C_; ++c) {
      const int kc = soffs[c];
      rank += (int)((kc < key) | ((kc == key) & (c < tid)));
    }
    sd[rank] = tid;
  }
  __syncthreads();
  if (tid == 0) {
    // dilation-pure items: one per contiguous run (split at 32 rows)
    int ni = 0, c = 0;
    while (c < C_ && ni < MAX_ITEMS) {
      const int d = soffs[sd[c]];
      int e = c;
      while (e < C_ && soffs[sd[e]] == d) ++e;  // run [c, e)
      for (int st = c; st < e && ni < MAX_ITEMS; st += 32) {
        sd[66 + ni] = d;
        sd[78 + ni] = st;
        sd[90 + ni] = (e - st) < 32 ? (e - st) : 32;
        ++ni;
      }
      c = e;
    }
    sd[64] = ni;
  }
  __syncthreads();

  const int sbid = bid - nrow;
  if (sbid == 0) {
    if (tid < 102) desc[tid] = sd[tid];
    return;
  }
  const int wix = sbid - 1;
  if (wix >= sd[64]) return;
  const int start = sd[78 + wix];
  const int g = sd[90 + wix];

  // Pack A-frags: wpack[wix*2304 + ((ks*9+tap)*64+lane)], element layout
  // m = lane&31 (compressed row), k = (lane>>5)*8 + j, ic = ks*16 + k.
  for (int i = tid; i < 4 * 9 * 64; i += 256) {
    const int ks = i / 576;
    const int r = i % 576;
    const int tap = r >> 6;
    const int lane = r & 63;
    const int m = lane & 31, hh = lane >> 5;
    const bool act = m < g;
    const int oc = act ? sd[start + m] : 0;
    unsigned ww[4];
    for (int jj = 0; jj < 4; ++jj) {
      float v0 = 0.f, v1 = 0.f;
      if (act) {
        const int ic0 = ks * 16 + hh * 8 + jj * 2;
        v0 = w[(oc * C_ + ic0) * 9 + tap];
        v1 = w[(oc * C_ + ic0 + 1) * 9 + tap];
      }
      ww[jj] = bf16rne(v0) | (bf16rne(v1) << 16);
    }
    wpack[(size_t)wix * 2304 + i] = make_uint4(ww[0], ww[1], ww[2], ww[3]);
  }
}

template <bool PRE>
__global__ __launch_bounds__(1024, 4) void gsd_conv(
    const float* __restrict__ x, const unsigned short* __restrict__ xb16,
    const int* __restrict__ desc, const uint4* __restrict__ wpack,
    float* __restrict__ out) {
  const int tid = threadIdx.x;
  const int bid0 = blockIdx.x;
  const int gxid = (bid0 & 7) * 64 + (bid0 >> 3);  // XCD swizzle (512%8==0)
  const int b = gxid >> 5;
  const int yt = (gxid >> 2) & 7;
  const int xt = gxid & 3;
  const int y0 = yt * 16, x0 = xt * 32;

  const int lane = tid & 63;
  const int n = lane & 31;    // MFMA B col -> output x
  const int h = lane >> 5;    // k-half
  const int wv = tid >> 6;    // 16 waves
  const int yp = wv & 7;      // y-pair index
  const int par = wv >> 3;    // item parity
  const int yb = yp * 2;      // this wave's rows: yb, yb+1

  // all 4 ks-planes resident: 159744 B -> 1 block/CU, 16 waves (4/SIMD)
  __shared__ __align__(16) unsigned ldsbuf[4 * BUFDW];

  if constexpr (PRE) {
    // ---- stage all 4 planes: <=12 async 16B chunks/wave, zero VALU ----
    // Chunk-set s covers chunks q = s*64 + lane; LDS dst byte = q*16
    // (linear). Slot (pix,p) holds logical ic-half p ^ f(pix),
    // f(pix)=(pix>>2)&1 (bank swizzle via the global source address).
    // Wave w handles sets {w, w+16, w+32 (w<7)}.
    const unsigned short* xbase = xb16 + (size_t)b * 4 * PLANE_STRIDE;
    int srcoff[3];
#pragma unroll
    for (int j = 0; j < 3; ++j) {
      const int q = (wv + j * 16) * 64 + lane;
      int pix = q >> 1;
      if (pix > NPIX - 1) pix = NPIX - 1;  // tail -> pad, src clamped
      const int p = q & 1;
      const int yy = pix / EX, xx = pix - yy * EX;
      const int half = p ^ ((pix >> 2) & 1);
      srcoff[j] = ((y0 + yy) * PADW + (x0 + xx)) * 16 + half * 8;
    }
#pragma unroll
    for (int ks = 0; ks < 4; ++ks) {
      const unsigned short* xp = xbase + (size_t)ks * PLANE_STRIDE;
#pragma unroll
      for (int j = 0; j < 3; ++j) {
        if (j < 2 || wv < 7) {  // sets 0..38 only
          GLOAD_LDS16(xp + srcoff[j],
                      &ldsbuf[ks * BUFDW + (wv + j * 16) * 256]);
        }
      }
    }
  } else {
    // ---- fallback: stage 4 planes via fp32 loads + VALU convert ----
    const int slx = tid & 63;
    const int sq = (tid >> 6) & 3;
    const int sy4 = tid >> 8;  // 0..3
    const float* xb = x + (size_t)b * (C_ * HW_ * HW_);
    const int gx = x0 - 6 + slx;
    const int gxc = gx < 0 ? 0 : (gx > 127 ? 127 : gx);
    const bool xin = ((unsigned)gx < 128u) & (slx < EX);
    for (int ks = 0; ks < 4; ++ks) {
      const float* xp = xb + (size_t)(ks * 16 + sq * 4) * (HW_ * HW_);
#pragma unroll 2
      for (int yy = sy4; yy < EY; yy += 4) {
        const int gy = y0 - 6 + yy;
        const int gyc = gy < 0 ? 0 : (gy > 127 ? 127 : gy);
        const bool ok = xin & ((unsigned)gy < 128u);
        const float* p = xp + gyc * HW_ + gxc;
        float v0 = p[0];
        float v1 = p[HW_ * HW_];
        float v2 = p[2 * HW_ * HW_];
        float v3 = p[3 * HW_ * HW_];
        if (!ok) { v0 = v1 = v2 = v3 = 0.f; }
        const unsigned lo = bf16rne(v0) | (bf16rne(v1) << 16);
        const unsigned hi = bf16rne(v2) | (bf16rne(v3) << 16);
        if (slx < EX) {
          const int pix = yy * EX + slx;
          const int dws = ks * BUFDW + pix * 8 +
                          (((sq >> 1) ^ ((pix >> 2) & 1)) << 2) +
                          ((sq & 1) << 1);
          *reinterpret_cast<uint2*>(&ldsbuf[dws]) = make_uint2(lo, hi);
        }
      }
    }
  }
  __syncthreads();  // single barrier; compute is barrier-free

  const int cnt = __builtin_amdgcn_readfirstlane(desc[64]);

  // ---- item-outer compute: items s==par (mod 2); one acc pair live ----
  for (int s = par; s < cnt; s += 2) {
    const int d = __builtin_amdgcn_readfirstlane(desc[66 + s]);
    const int start = __builtin_amdgcn_readfirstlane(desc[78 + s]);
    const int g = __builtin_amdgcn_readfirstlane(desc[90 + s]);

    floatx16 acc0, acc1;
#pragma unroll
    for (int e = 0; e < 16; ++e) { acc0[e] = 0.f; acc1[e] = 0.f; }

#pragma unroll
    for (int ks = 0; ks < 4; ++ks) {
      const uint4* wp = wpack + ((size_t)s * 4 + ks) * 576 + lane;
      const unsigned* cbuf = &ldsbuf[ks * BUFDW];
#pragma unroll
      for (int tap = 0; tap < 9; ++tap) {
        const int ky = tap / 3 - 1, kx = tap % 3 - 1;
        const short8 af = __builtin_bit_cast(short8, wp[tap * 64]);
        const int prow = yb + ky * d + 6;
        const int pxb = n + kx * d + 6;
        const int pix0 = prow * EX + pxb;
        const int pix1 = pix0 + EX;
        const int dws0 = (pix0 << 3) + ((h ^ ((pix0 >> 2) & 1)) << 2);
        const int dws1 = (pix1 << 3) + ((h ^ ((pix1 >> 2) & 1)) << 2);
        const short8 bf0 = *reinterpret_cast<const short8*>(&cbuf[dws0]);
        const short8 bf1 = *reinterpret_cast<const short8*>(&cbuf[dws1]);
        acc0 = __builtin_amdgcn_mfma_f32_32x32x16_bf16(af, bf0, acc0, 0, 0, 0);
        acc1 = __builtin_amdgcn_mfma_f32_32x32x16_bf16(af, bf1, acc1, 0, 0, 0);
      }
    }

    // ---- store item s: D col=lane&31 -> x, row=(reg&3)+8*(reg>>2)+4*h ----
    // row is the compressed item row; mask row<g, oc = perm[start+row].
#pragma unroll
    for (int reg = 0; reg < 16; ++reg) {
      const int row = (reg & 3) + 8 * (reg >> 2) + 4 * h;
      if (row < g) {
        const int oc = desc[start + row];
        float* op =
            &out[((size_t)(b * C_ + oc) * HW_ + (y0 + yb)) * HW_ + x0 + n];
        op[0] = acc0[reg];
        op[HW_] = acc1[reg];
      }
    }
  }
}

extern "C" void kernel_launch(void* const* d_in, const int* in_sizes, int n_in,
                              void* d_out, int out_size, void* d_ws,
                              size_t ws_size, hipStream_t stream) {
  const float* x = (const float*)d_in[0];    // [16,64,128,128] fp32
  const float* w = (const float*)d_in[1];    // [64,64,3,3] fp32
  const int* offsets = (const int*)d_in[2];  // [64] int32 in [1,6]
  float* out = (float*)d_out;                // [16,64,128,128] fp32

  int* desc = (int*)d_ws;
  uint4* wpack = (uint4*)((char*)d_ws + WS_WPACK_OFF);  // 442368 B
  unsigned short* xb16 = (unsigned short*)((char*)d_ws + WS_XB16_OFF);

  // Fast path needs 1 MB (desc+wpack) + 40.1 MB (xb16) of workspace.
  const bool pre = ws_size >= (size_t)WS_XB16_OFF + XB16_BYTES;
  const int nrow = pre ? B_ * PADW : 0;

  gsd_prep<<<dim3(nrow + 1 + MAX_ITEMS), 256, 0, stream>>>(
      x, offsets, w, desc, wpack, xb16, nrow);
  if (pre) {
    gsd_conv<true><<<dim3(B_ * 8 * 4), 1024, 0, stream>>>(
        x, xb16, desc, wpack, out);
  } else {
    gsd_conv<false><<<dim3(B_ * 8 * 4), 1024, 0, stream>>>(
        x, xb16, desc, wpack, out);
  }
}